// Round 9
// baseline (66.894 us; speedup 1.0000x reference)
//
#include <hip/hip_runtime.h>
#include <math.h>

#define B_SZ 4
#define C_IN 64
#define HW_ 576
#define NBLK 256
#define NTHR 576
#define PPLANE 728                    // 26*28 padded plane of h2 (channel pair)
#define XH_N   (B_SZ * 32 * PPLANE)   // 93184
#define WQH_N  (192 * 32 * 9)         // 55296: ((g*32+icp)*3+o)*9+t, oc=g+64*o
#define WOH_N  (64 * 32 * 9)          // 18432: (oc*32+icp)*9+t

typedef _Float16 h2 __attribute__((ext_vector_type(2)));
typedef _Float16 h4 __attribute__((ext_vector_type(4)));

static __device__ __forceinline__ h2 lo2(h4 v) { return __builtin_shufflevector(v, v, 0, 1); }
static __device__ __forceinline__ h2 hi2(h4 v) { return __builtin_shufflevector(v, v, 2, 3); }

static __device__ __forceinline__ float dot2(h2 a, h2 b, float c) {
#if __has_builtin(__builtin_amdgcn_fdot2)
  return __builtin_amdgcn_fdot2(a, b, c, false);
#else
  return c + (float)a.x * (float)b.x + (float)a.y * (float)b.y;
#endif
}

static __device__ __forceinline__ float frcp(float d) {
#if __has_builtin(__builtin_amdgcn_rcpf)
  return __builtin_amdgcn_rcpf(d);
#else
  return 1.0f / d;
#endif
}

// Device-wide barrier, R5-bug-fixed: release/acquire bulk cache ops run ONCE
// per block (thread 0), and the spin polls with RELAXED agent loads (reads
// IC, no per-iteration invalidate). Co-residency is capacity-guaranteed:
// 256 blocks x 9 waves, <=27KB LDS -> every CU hosts >=1 block immediately.
static __device__ __forceinline__ void gbar(unsigned* cnt, unsigned target) {
  __syncthreads();
  if (threadIdx.x == 0) {
    __hip_atomic_fetch_add(cnt, 1u, __ATOMIC_RELEASE, __HIP_MEMORY_SCOPE_AGENT);
    while (__hip_atomic_load(cnt, __ATOMIC_RELAXED, __HIP_MEMORY_SCOPE_AGENT) < target)
      __builtin_amdgcn_s_sleep(8);
    __builtin_amdgcn_fence(__ATOMIC_ACQUIRE, "agent");
  }
  __syncthreads();
}

__global__ __launch_bounds__(NTHR)
void fused_kernel(const float* __restrict__ x, const float* __restrict__ gamma,
                  const float* __restrict__ beta, const float* __restrict__ wq,
                  const float* __restrict__ wo, float* __restrict__ out,
                  float* __restrict__ A, float* __restrict__ Bc,
                  h2* __restrict__ xh, h2* __restrict__ wqh,
                  h2* __restrict__ woh, h2* __restrict__ outv,
                  unsigned* __restrict__ barcnt) {
  const int bid = blockIdx.x;
  const int tid = threadIdx.x;
  __shared__ __align__(16) char smem[26080];
  // region map: [0,6912) Wl/cb/P1red/P5 | [6912,11520) kvs | [11520,13824) qs
  // [13824,14472) red | [14472,14544) FGf | [14560,26080) red2[144][20]

  // ---------------- P1: BN batch stats -> A,Bc (blocks 0..63) --------------
  if (bid < 64) {
    const int c = bid;
    float s = 0.f, ss = 0.f;
    for (int j = tid; j < B_SZ * HW_; j += NTHR) {
      int b = j / HW_, i = j - b * HW_;
      float v = x[(b * C_IN + c) * HW_ + i];
      s += v; ss = fmaf(v, v, ss);
    }
#pragma unroll
    for (int off = 32; off > 0; off >>= 1) {
      s += __shfl_down(s, off);
      ss += __shfl_down(ss, off);
    }
    float* red1 = (float*)smem;
    if ((tid & 63) == 0) { red1[tid >> 6] = s; red1[16 + (tid >> 6)] = ss; }
    __syncthreads();
    if (tid == 0) {
      s = 0.f; ss = 0.f;
      for (int w = 0; w < 9; ++w) { s += red1[w]; ss += red1[16 + w]; }
      const float inv_n = 1.f / (B_SZ * HW_);
      float mean = s * inv_n;
      float var  = ss * inv_n - mean * mean;
      float a = rsqrtf(var + 1e-5f) * gamma[c];
      A[c]  = a;
      Bc[c] = fmaf(-mean, a, beta[c]);
    }
  }
  gbar(barcnt, 1 * NBLK);

  // ---------------- P2: pack xn + weights to f16 ---------------------------
  for (int t = bid * NTHR + tid; t < XH_N + WQH_N + WOH_N; t += NBLK * NTHR) {
    if (t < XH_N) {
      int b = t / (32 * PPLANE);
      int r0 = t - b * (32 * PPLANE);
      int icp = r0 / PPLANE;
      int rr = r0 - icp * PPLANE;
      int rrow = rr / 28, e = rr - rrow * 28;
      int yy = rrow - 1, xx = e - 1;
      float f0 = 0.f, f1 = 0.f;
      if ((unsigned)yy < 24u && (unsigned)xx < 24u) {
        int c0 = icp * 2;
        int base = ((b * C_IN + c0) * HW_) + yy * 24 + xx;
        f0 = fmaf(x[base], A[c0], Bc[c0]);
        f1 = fmaf(x[base + HW_], A[c0 + 1], Bc[c0 + 1]);
      }
      h2 v; v.x = (_Float16)f0; v.y = (_Float16)f1;
      xh[t] = v;
    } else if (t < XH_N + WQH_N) {
      int t0 = t - XH_N;
      int tt = t0 % 9; int r = t0 / 9;
      int o = r % 3; r /= 3;
      int icp = r % 32; int g = r / 32;
      int oc = g + 64 * o, ic = icp * 2;   // q/k/v of channel g in one block
      h2 v;
      v.x = (_Float16)wq[(oc * C_IN + ic) * 9 + tt];
      v.y = (_Float16)wq[(oc * C_IN + ic + 1) * 9 + tt];
      wqh[t0] = v;
    } else {
      int t0 = t - XH_N - WQH_N;
      int tt = t0 % 9; int r = t0 / 9;
      int icp = r % 32; int oc = r / 32;
      int ic = icp * 2;
      h2 v;  // scale 4096: dodge f16 subnormals (w_out ~ 7e-5)
      v.x = (_Float16)(wo[(oc * C_IN + ic) * 9 + tt] * 4096.f);
      v.y = (_Float16)(wo[(oc * C_IN + ic + 1) * 9 + tt] * 4096.f);
      woh[t0] = v;
    }
  }
  gbar(barcnt, 2 * NBLK);

  // ---------------- P3: qkv conv, block=(b,c), oc={c,64+c,128+c} -----------
  {
    const int b = bid >> 6, c = bid & 63;
    const int sub = tid / 288;
    const int r = tid - sub * 288;
    const int y = r / 12, x0 = (r % 12) * 2;

    h2*    Wl  = (h2*)smem;               // [32][28] h2
    float* cb  = (float*)smem;            // [3][288][2] f32 (combine)
    float2* kvs = (float2*)(smem + 6912);
    float* qs  = (float*)(smem + 11520);
    float* red = (float*)(smem + 13824);
    float* FGf = (float*)(smem + 14472);
    float* red2 = (float*)(smem + 14560); // [144][20]

    for (int j = tid; j < 864; j += NTHR) {
      int icp = j / 27, rem = j - icp * 27;
      Wl[icp * 28 + rem] = wqh[c * 864 + j];
    }
    __syncthreads();

    float acc[3][2] = {{0.f, 0.f}, {0.f, 0.f}, {0.f, 0.f}};
    const int icp0 = sub * 16;
    for (int i = 0; i < 16; ++i) {
      const int icp = icp0 + i;
      const h2* wrow = Wl + icp * 28;
      h2 W[27];
#pragma unroll
      for (int tt = 0; tt < 27; ++tt) W[tt] = wrow[tt];
      const h2* dp = xh + ((size_t)(b * 32 + icp) * PPLANE + y * 28 + x0);
      h4 r0a = *(const h4*)(dp);      h4 r0b = *(const h4*)(dp + 2);
      h4 r1a = *(const h4*)(dp + 28); h4 r1b = *(const h4*)(dp + 30);
      h4 r2a = *(const h4*)(dp + 56); h4 r2b = *(const h4*)(dp + 58);
#pragma unroll
      for (int o = 0; o < 3; ++o) {
        const h2* w9 = W + o * 9;
        float a0 = acc[o][0], a1 = acc[o][1];
        a0 = dot2(lo2(r0a), w9[0], a0);  a1 = dot2(hi2(r0a), w9[0], a1);
        a0 = dot2(hi2(r0a), w9[1], a0);  a1 = dot2(lo2(r0b), w9[1], a1);
        a0 = dot2(lo2(r0b), w9[2], a0);  a1 = dot2(hi2(r0b), w9[2], a1);
        a0 = dot2(lo2(r1a), w9[3], a0);  a1 = dot2(hi2(r1a), w9[3], a1);
        a0 = dot2(hi2(r1a), w9[4], a0);  a1 = dot2(lo2(r1b), w9[4], a1);
        a0 = dot2(lo2(r1b), w9[5], a0);  a1 = dot2(hi2(r1b), w9[5], a1);
        a0 = dot2(lo2(r2a), w9[6], a0);  a1 = dot2(hi2(r2a), w9[6], a1);
        a0 = dot2(hi2(r2a), w9[7], a0);  a1 = dot2(lo2(r2b), w9[7], a1);
        a0 = dot2(lo2(r2b), w9[8], a0);  a1 = dot2(hi2(r2b), w9[8], a1);
        acc[o][0] = a0; acc[o][1] = a1;
      }
    }
    __syncthreads();                      // Wl dead; cb overlays it
    if (sub == 1) {
#pragma unroll
      for (int o = 0; o < 3; ++o) {
        cb[(o * 288 + r) * 2 + 0] = acc[o][0];
        cb[(o * 288 + r) * 2 + 1] = acc[o][1];
      }
    }
    __syncthreads();
    const float scale_l2e = 0.125f * 1.44269504088896341f;  // 1/sqrt(64)*log2e
    if (sub == 0) {
      float q0 = acc[0][0] + cb[(0 * 288 + r) * 2 + 0];
      float q1 = acc[0][1] + cb[(0 * 288 + r) * 2 + 1];
      float k0 = acc[1][0] + cb[(1 * 288 + r) * 2 + 0];
      float k1 = acc[1][1] + cb[(1 * 288 + r) * 2 + 1];
      float v0 = acc[2][0] + cb[(2 * 288 + r) * 2 + 0];
      float v1 = acc[2][1] + cb[(2 * 288 + r) * 2 + 1];
      qs[2 * r] = q0 * scale_l2e; qs[2 * r + 1] = q1 * scale_l2e;
      kvs[2 * r] = make_float2(k0, v0);
      kvs[2 * r + 1] = make_float2(k1, v1);
    }
    __syncthreads();

    // ---- P4: barycentric rank-1 attention (thread tid = pixel tid) ----
    const float s = qs[tid];
    float smax = s, smin = s;
#pragma unroll
    for (int off = 32; off > 0; off >>= 1) {
      smax = fmaxf(smax, __shfl_down(smax, off));
      smin = fminf(smin, __shfl_down(smin, off));
    }
    const int wid = tid >> 6;
    if ((tid & 63) == 0) { red[wid] = smax; red[10 + wid] = smin; }
    __syncthreads();
    smax = red[0]; smin = red[10];
#pragma unroll
    for (int w = 1; w < 9; ++w) {
      smax = fmaxf(smax, red[w]); smin = fminf(smin, red[10 + w]);
    }
    const float cc = 0.5f * (smax + smin);
    const float rr = fmaxf(0.5f * (smax - smin), 1e-6f);
    const float COS[9] = { 0.98480775f,  0.86602540f,  0.64278761f,  0.34202014f, 0.f,
                          -0.34202014f, -0.64278761f, -0.86602540f, -0.98480775f };
    const float WJ[9]  = { 0.17364818f, -0.5f,  0.76604444f, -0.93969262f, 1.f,
                          -0.93969262f, 0.76604444f, -0.5f, 0.17364818f };
    float xj[9];
#pragma unroll
    for (int j = 0; j < 9; ++j) xj[j] = fmaf(rr, COS[j], cc);

    const float kk = kvs[tid].x, vv = kvs[tid].y;
    float fj[9], gj[9];
#pragma unroll
    for (int j = 0; j < 9; ++j) {
      float E = __builtin_amdgcn_exp2f(xj[j] * kk);
      gj[j] = E; fj[j] = E * vv;
    }
    // 2-level fold (4-lane groups), LDS transpose, 8-thread column sums.
#pragma unroll
    for (int j = 0; j < 9; ++j) {
      fj[j] += __shfl_xor(fj[j], 1); gj[j] += __shfl_xor(gj[j], 1);
      fj[j] += __shfl_xor(fj[j], 2); gj[j] += __shfl_xor(gj[j], 2);
    }
    if ((tid & 3) == 0) {
      const int row = tid >> 2;       // 0..143
#pragma unroll
      for (int j = 0; j < 9; ++j) {
        red2[row * 20 + j] = fj[j];
        red2[row * 20 + 9 + j] = gj[j];
      }
    }
    __syncthreads();
    if (tid < 144) {
      const int j = tid >> 3, chunk = tid & 7;   // j in 0..17
      float sum = 0.f;
#pragma unroll
      for (int i = 0; i < 18; ++i) sum += red2[(chunk + 8 * i) * 20 + j];
      sum += __shfl_xor(sum, 1);
      sum += __shfl_xor(sum, 2);
      sum += __shfl_xor(sum, 4);
      if (chunk == 0) FGf[j] = sum;
    }
    __syncthreads();

    float num = 0.f, den = 0.f;
#pragma unroll
    for (int j = 0; j < 9; ++j) {
      float d = s - xj[j];
      d = copysignf(fmaxf(fabsf(d), 1e-7f), d);
      float mu = WJ[j] * frcp(d);
      num = fmaf(mu, FGf[j], num);
      den = fmaf(mu, FGf[9 + j], den);
    }
    float outval = num / den;

    const int icp = c >> 1, hc = c & 1;
    _Float16* plane = reinterpret_cast<_Float16*>(outv + ((size_t)(b * 32) + icp) * PPLANE);
    const int yy = tid / 24, xx = tid - yy * 24;
    plane[((yy + 1) * 28 + (xx + 1)) * 2 + hc] = (_Float16)outval;
    if (tid < 100) {  // zero halo (cols 26,27 never read)
      int rrow, e;
      if (tid < 26)      { rrow = 0;            e = tid; }
      else if (tid < 52) { rrow = 25;           e = tid - 26; }
      else if (tid < 76) { rrow = tid - 52 + 1; e = 0; }
      else               { rrow = tid - 76 + 1; e = 25; }
      plane[(rrow * 28 + e) * 2 + hc] = (_Float16)0.f;
    }
  }
  gbar(barcnt, 3 * NBLK);

  // ---------------- P5: out conv (OCG=1) + residual + final store ----------
  {
    const int b = bid >> 6, oc = bid & 63;
    const int sub = tid / 288;
    const int r = tid - sub * 288;
    const int y = r / 12, x0 = (r % 12) * 2;

    h2* Wl = (h2*)smem;                 // [32 icp][12 h2] (9 used)
    for (int j = tid; j < 288; j += NTHR) {
      int icp = j / 9, rem = j - icp * 9;
      Wl[icp * 12 + rem] = woh[oc * 288 + j];
    }
    __syncthreads();

    float a0 = 0.f, a1 = 0.f;
    const int icp0 = sub * 16;
    for (int i = 0; i < 16; ++i) {
      const int icp = icp0 + i;
      const h2* w9r = Wl + icp * 12;
      h2 W[9];
#pragma unroll
      for (int tt = 0; tt < 9; ++tt) W[tt] = w9r[tt];
      const h2* dp = outv + ((size_t)(b * 32 + icp) * PPLANE + y * 28 + x0);
      h4 r0a = *(const h4*)(dp);      h4 r0b = *(const h4*)(dp + 2);
      h4 r1a = *(const h4*)(dp + 28); h4 r1b = *(const h4*)(dp + 30);
      h4 r2a = *(const h4*)(dp + 56); h4 r2b = *(const h4*)(dp + 58);
      a0 = dot2(lo2(r0a), W[0], a0);  a1 = dot2(hi2(r0a), W[0], a1);
      a0 = dot2(hi2(r0a), W[1], a0);  a1 = dot2(lo2(r0b), W[1], a1);
      a0 = dot2(lo2(r0b), W[2], a0);  a1 = dot2(hi2(r0b), W[2], a1);
      a0 = dot2(lo2(r1a), W[3], a0);  a1 = dot2(hi2(r1a), W[3], a1);
      a0 = dot2(hi2(r1a), W[4], a0);  a1 = dot2(lo2(r1b), W[4], a1);
      a0 = dot2(lo2(r1b), W[5], a0);  a1 = dot2(hi2(r1b), W[5], a1);
      a0 = dot2(lo2(r2a), W[6], a0);  a1 = dot2(hi2(r2a), W[6], a1);
      a0 = dot2(hi2(r2a), W[7], a0);  a1 = dot2(lo2(r2b), W[7], a1);
      a0 = dot2(lo2(r2b), W[8], a0);  a1 = dot2(hi2(r2b), W[8], a1);
    }
    __syncthreads();
    float* cb = (float*)smem;           // [288][2]
    if (sub == 1) { cb[r * 2] = a0; cb[r * 2 + 1] = a1; }
    __syncthreads();
    if (sub == 0) {
      size_t idx = ((size_t)(b * C_IN + oc) * HW_) + y * 24 + x0;
      float2 xr = *reinterpret_cast<const float2*>(x + idx);
      const float inv = 1.f / 4096.f;
      float2 v;
      v.x = fmaf(a0 + cb[r * 2],     inv, xr.x);
      v.y = fmaf(a1 + cb[r * 2 + 1], inv, xr.y);
      *reinterpret_cast<float2*>(out + idx) = v;
    }
  }
}

// ---------------- launch ---------------------------------------------------
extern "C" void kernel_launch(void* const* d_in, const int* in_sizes, int n_in,
                              void* d_out, int out_size, void* d_ws, size_t ws_size,
                              hipStream_t stream) {
  const float* x     = (const float*)d_in[0];
  const float* gamma = (const float*)d_in[1];
  const float* beta  = (const float*)d_in[2];
  const float* w_qkv = (const float*)d_in[3];
  const float* w_out = (const float*)d_in[4];
  float* out = (float*)d_out;

  float* A   = (float*)d_ws;
  float* Bc  = A + 64;
  h2* xh     = (h2*)(Bc + 64);
  h2* wqh    = xh + XH_N;
  h2* woh    = wqh + WQH_N;
  h2* outv   = woh + WOH_N;
  unsigned* barcnt = (unsigned*)(outv + XH_N);

  hipMemsetAsync(barcnt, 0, 128, stream);
  fused_kernel<<<NBLK, NTHR, 0, stream>>>(x, gamma, beta, w_qkv, w_out, out,
                                          A, Bc, xh, wqh, woh, outv, barcnt);
}

// Round 11
// 26.076 us; speedup vs baseline: 2.5654x; 2.5654x over previous
//
#include <hip/hip_runtime.h>
#include <math.h>

#define B_SZ 4
#define C_IN 64
#define HW_ 576
#define PPLANE 728                    // 26*28 padded plane of h2 (channel pair)
#define XH_N   (B_SZ * 32 * PPLANE)   // 93184
#define WQH_N  (192 * 32 * 9)         // 55296: ((g*32+icp)*3+o)*9+t, oc=g+64*o
#define WOH_N  (64 * 32 * 9)          // 18432: (oc*32+icp)*9+t

typedef _Float16 h2 __attribute__((ext_vector_type(2)));
typedef _Float16 h4 __attribute__((ext_vector_type(4)));
typedef _Float16 h8 __attribute__((ext_vector_type(8)));

static __device__ __forceinline__ h2 lo2(h4 v) { return __builtin_shufflevector(v, v, 0, 1); }
static __device__ __forceinline__ h2 hi2(h4 v) { return __builtin_shufflevector(v, v, 2, 3); }

static __device__ __forceinline__ float dot2(h2 a, h2 b, float c) {
#if __has_builtin(__builtin_amdgcn_fdot2)
  return __builtin_amdgcn_fdot2(a, b, c, false);
#else
  return c + (float)a.x * (float)b.x + (float)a.y * (float)b.y;
#endif
}

static __device__ __forceinline__ float frcp(float d) {
#if __has_builtin(__builtin_amdgcn_rcpf)
  return __builtin_amdgcn_rcpf(d);
#else
  return 1.0f / d;
#endif
}

// ---------------- K1: BN stats (redundant per block) + pack x & weights ----
__global__ __launch_bounds__(256)
void stats_pack_kernel(const float* __restrict__ x, const float* __restrict__ gamma,
                       const float* __restrict__ beta, const float* __restrict__ wq,
                       const float* __restrict__ wo, h2* __restrict__ xh,
                       h2* __restrict__ wqh, h2* __restrict__ woh) {
  const int bid = blockIdx.x, tid = threadIdx.x;
  if (bid < 128) {
    const int icp = bid & 31, b = bid >> 5;
    __shared__ float rs[4], rss[4], ab[4];
    const int c = icp * 2 + (tid >> 7);
    float s = 0.f, ss = 0.f;
    for (int i = (tid & 127); i < B_SZ * HW_; i += 128) {
      int b2 = i / HW_, px = i - b2 * HW_;
      float v = x[(b2 * C_IN + c) * HW_ + px];
      s += v; ss = fmaf(v, v, ss);
    }
#pragma unroll
    for (int off = 32; off > 0; off >>= 1) {
      s += __shfl_down(s, off); ss += __shfl_down(ss, off);
    }
    if ((tid & 63) == 0) { rs[tid >> 6] = s; rss[tid >> 6] = ss; }
    __syncthreads();
    if (tid < 2) {
      float S = rs[tid * 2] + rs[tid * 2 + 1], SS = rss[tid * 2] + rss[tid * 2 + 1];
      const float inv_n = 1.f / (B_SZ * HW_);
      float mean = S * inv_n;
      float var  = SS * inv_n - mean * mean;
      float a = rsqrtf(var + 1e-5f) * gamma[icp * 2 + tid];
      ab[tid * 2] = a;
      ab[tid * 2 + 1] = fmaf(-mean, a, beta[icp * 2 + tid]);
    }
    __syncthreads();
    const float a0 = ab[0], b0 = ab[1], a1 = ab[2], b1 = ab[3];
    h2* plane = xh + (size_t)(b * 32 + icp) * PPLANE;
    const float* src0 = x + (size_t)(b * C_IN + icp * 2) * HW_;
    for (int e = tid; e < PPLANE; e += 256) {
      int rrow = e / 28, ecol = e - rrow * 28;
      int yy = rrow - 1, xx = ecol - 1;
      float f0 = 0.f, f1 = 0.f;
      if ((unsigned)yy < 24u && (unsigned)xx < 24u) {
        f0 = fmaf(src0[yy * 24 + xx],       a0, b0);
        f1 = fmaf(src0[HW_ + yy * 24 + xx], a1, b1);
      }
      h2 v; v.x = (_Float16)f0; v.y = (_Float16)f1;
      plane[e] = v;
    }
  } else {
    const int base = (bid - 128) * 576;
    for (int t = base + tid; t < base + 576; t += 256) {
      if (t < WQH_N) {
        int tt = t % 9; int r = t / 9;
        int o = r % 3; r /= 3;
        int icp = r % 32; int g = r / 32;
        int oc = g + 64 * o, ic = icp * 2;   // q/k/v of channel g in one block
        h2 v;
        v.x = (_Float16)wq[(oc * C_IN + ic) * 9 + tt];
        v.y = (_Float16)wq[(oc * C_IN + ic + 1) * 9 + tt];
        wqh[t] = v;
      } else {
        int t0 = t - WQH_N;
        int tt = t0 % 9; int r = t0 / 9;
        int icp = r % 32; int oc = r / 32;
        int ic = icp * 2;
        h2 v;  // scale 4096: dodge f16 subnormals (w_out ~ 7e-5)
        v.x = (_Float16)(wo[(oc * C_IN + ic) * 9 + tt] * 4096.f);
        v.y = (_Float16)(wo[(oc * C_IN + ic + 1) * 9 + tt] * 4096.f);
        woh[t0] = v;
      }
    }
  }
}

// ---------------- K2: fused qkv conv + barycentric rank-1 attention --------
__global__ __launch_bounds__(576)
void qkv_attn_kernel(const h2* __restrict__ xh, const h2* __restrict__ wqh,
                     h2* __restrict__ outv) {
  const int bid = blockIdx.x, tid = threadIdx.x;
  const int b = bid >> 6, c = bid & 63;
  const int sub = tid / 288;
  const int r = tid - sub * 288;
  const int y = r / 12, x0 = (r % 12) * 2;

  __shared__ __align__(16) char smem[26080];
  h2*    Wl  = (h2*)smem;               // [32 rows][32 h2] = 4KB (conv phase)
  float* cb  = (float*)smem;            // [3][288][2] (combine; overlays Wl)
  float2* kvs = (float2*)(smem + 6912); // 576 float2
  float* qs  = (float*)(smem + 11520);  // 576 f32
  float* red = (float*)(smem + 13824);  // 20
  float* FGf = (float*)(smem + 14472);  // 18
  float* red2 = (float*)(smem + 14560); // [144][20]

  // stage weights: 27 used h2 per icp row, rows padded to 32 h2 (128B)
  for (int j = tid; j < 864; j += 576) {
    int icp = j / 27, rem = j - icp * 27;
    Wl[icp * 32 + rem] = wqh[c * 864 + j];
  }
  __syncthreads();

  float acc[3][2] = {{0.f, 0.f}, {0.f, 0.f}, {0.f, 0.f}};
  const int icp0 = sub * 16;
  const int yo = y * 28 + x0;
  const h2* dbase = xh + ((size_t)(b * 32 + icp0) * PPLANE + yo);
#pragma unroll
  for (int i = 0; i < 16; ++i) {
    const h2* dp = dbase + (size_t)i * PPLANE;
    h4 r0a = *(const h4*)(dp);      h4 r0b = *(const h4*)(dp + 2);
    h4 r1a = *(const h4*)(dp + 28); h4 r1b = *(const h4*)(dp + 30);
    h4 r2a = *(const h4*)(dp + 56); h4 r2b = *(const h4*)(dp + 58);
    const h2* wrow = Wl + (icp0 + i) * 32;
    // size-consistent union: v8[7] = 56 halves == v2[28] = 56 halves.
    // 7x 16B LDS loads cover v2[0..27] (indices 0..26 used).
    union { h8 v8[7]; h2 v2[28]; } W;
#pragma unroll
    for (int j8 = 0; j8 < 7; ++j8) W.v8[j8] = *(const h8*)(wrow + j8 * 4);
#pragma unroll
    for (int o = 0; o < 3; ++o) {
      float a0 = acc[o][0], a1 = acc[o][1];
      a0 = dot2(lo2(r0a), W.v2[o * 9 + 0], a0);  a1 = dot2(hi2(r0a), W.v2[o * 9 + 0], a1);
      a0 = dot2(hi2(r0a), W.v2[o * 9 + 1], a0);  a1 = dot2(lo2(r0b), W.v2[o * 9 + 1], a1);
      a0 = dot2(lo2(r0b), W.v2[o * 9 + 2], a0);  a1 = dot2(hi2(r0b), W.v2[o * 9 + 2], a1);
      a0 = dot2(lo2(r1a), W.v2[o * 9 + 3], a0);  a1 = dot2(hi2(r1a), W.v2[o * 9 + 3], a1);
      a0 = dot2(hi2(r1a), W.v2[o * 9 + 4], a0);  a1 = dot2(lo2(r1b), W.v2[o * 9 + 4], a1);
      a0 = dot2(lo2(r1b), W.v2[o * 9 + 5], a0);  a1 = dot2(hi2(r1b), W.v2[o * 9 + 5], a1);
      a0 = dot2(lo2(r2a), W.v2[o * 9 + 6], a0);  a1 = dot2(hi2(r2a), W.v2[o * 9 + 6], a1);
      a0 = dot2(hi2(r2a), W.v2[o * 9 + 7], a0);  a1 = dot2(lo2(r2b), W.v2[o * 9 + 7], a1);
      a0 = dot2(lo2(r2b), W.v2[o * 9 + 8], a0);  a1 = dot2(hi2(r2b), W.v2[o * 9 + 8], a1);
      acc[o][0] = a0; acc[o][1] = a1;
    }
  }
  __syncthreads();                      // Wl dead; cb overlays it
  if (sub == 1) {
#pragma unroll
    for (int o = 0; o < 3; ++o) {
      cb[(o * 288 + r) * 2 + 0] = acc[o][0];
      cb[(o * 288 + r) * 2 + 1] = acc[o][1];
    }
  }
  __syncthreads();
  const float scale_l2e = 0.125f * 1.44269504088896341f;  // 1/sqrt(64)*log2(e)
  if (sub == 0) {
    float q0 = acc[0][0] + cb[(0 * 288 + r) * 2 + 0];
    float q1 = acc[0][1] + cb[(0 * 288 + r) * 2 + 1];
    float k0 = acc[1][0] + cb[(1 * 288 + r) * 2 + 0];
    float k1 = acc[1][1] + cb[(1 * 288 + r) * 2 + 1];
    float v0 = acc[2][0] + cb[(2 * 288 + r) * 2 + 0];
    float v1 = acc[2][1] + cb[(2 * 288 + r) * 2 + 1];
    qs[2 * r] = q0 * scale_l2e; qs[2 * r + 1] = q1 * scale_l2e;
    kvs[2 * r] = make_float2(k0, v0);
    kvs[2 * r + 1] = make_float2(k1, v1);
  }
  __syncthreads();

  // ---- barycentric rank-1 attention (thread tid = pixel tid) ----
  const float s = qs[tid];
  float smax = s, smin = s;
#pragma unroll
  for (int off = 32; off > 0; off >>= 1) {
    smax = fmaxf(smax, __shfl_down(smax, off));
    smin = fminf(smin, __shfl_down(smin, off));
  }
  const int wid = tid >> 6;
  if ((tid & 63) == 0) { red[wid] = smax; red[10 + wid] = smin; }
  __syncthreads();
  smax = red[0]; smin = red[10];
#pragma unroll
  for (int w = 1; w < 9; ++w) {
    smax = fmaxf(smax, red[w]); smin = fminf(smin, red[10 + w]);
  }
  const float cc = 0.5f * (smax + smin);
  const float rr = fmaxf(0.5f * (smax - smin), 1e-6f);
  const float COS[9] = { 0.98480775f,  0.86602540f,  0.64278761f,  0.34202014f, 0.f,
                        -0.34202014f, -0.64278761f, -0.86602540f, -0.98480775f };
  const float WJ[9]  = { 0.17364818f, -0.5f,  0.76604444f, -0.93969262f, 1.f,
                        -0.93969262f, 0.76604444f, -0.5f, 0.17364818f };
  float xj[9];
#pragma unroll
  for (int j = 0; j < 9; ++j) xj[j] = fmaf(rr, COS[j], cc);

  const float kk = kvs[tid].x, vv = kvs[tid].y;
  float fj[9], gj[9];
#pragma unroll
  for (int j = 0; j < 9; ++j) {
    float E = __builtin_amdgcn_exp2f(xj[j] * kk);
    gj[j] = E; fj[j] = E * vv;
  }
  // 2-level fold (4-lane groups), LDS transpose, 8-thread column sums.
#pragma unroll
  for (int j = 0; j < 9; ++j) {
    fj[j] += __shfl_xor(fj[j], 1); gj[j] += __shfl_xor(gj[j], 1);
    fj[j] += __shfl_xor(fj[j], 2); gj[j] += __shfl_xor(gj[j], 2);
  }
  if ((tid & 3) == 0) {
    const int row = tid >> 2;       // 0..143
#pragma unroll
    for (int j = 0; j < 9; ++j) {
      red2[row * 20 + j] = fj[j];
      red2[row * 20 + 9 + j] = gj[j];
    }
  }
  __syncthreads();
  if (tid < 144) {
    const int j = tid >> 3, chunk = tid & 7;   // j in 0..17
    float sum = 0.f;
#pragma unroll
    for (int i = 0; i < 18; ++i) sum += red2[(chunk + 8 * i) * 20 + j];
    sum += __shfl_xor(sum, 1);
    sum += __shfl_xor(sum, 2);
    sum += __shfl_xor(sum, 4);
    if (chunk == 0) FGf[j] = sum;
  }
  __syncthreads();

  float num = 0.f, den = 0.f;
#pragma unroll
  for (int j = 0; j < 9; ++j) {
    float d = s - xj[j];
    d = copysignf(fmaxf(fabsf(d), 1e-7f), d);
    float mu = WJ[j] * frcp(d);
    num = fmaf(mu, FGf[j], num);
    den = fmaf(mu, FGf[9 + j], den);
  }
  float outval = num / den;

  const int icp = c >> 1, hc = c & 1;
  _Float16* plane = reinterpret_cast<_Float16*>(outv + ((size_t)(b * 32) + icp) * PPLANE);
  const int yy = tid / 24, xx = tid - yy * 24;
  plane[((yy + 1) * 28 + (xx + 1)) * 2 + hc] = (_Float16)outval;
  if (tid < 100) {  // zero halo (cols 26,27 never read)
    int rrow, e;
    if (tid < 26)      { rrow = 0;            e = tid; }
    else if (tid < 52) { rrow = 25;           e = tid - 26; }
    else if (tid < 76) { rrow = tid - 52 + 1; e = 0; }
    else               { rrow = tid - 76 + 1; e = 25; }
    plane[(rrow * 28 + e) * 2 + hc] = (_Float16)0.f;
  }
}

// ---------------- K3: out conv (OCG=1) + residual + final store ------------
__global__ __launch_bounds__(576)
void conv_out_kernel(const h2* __restrict__ outv, const h2* __restrict__ woh,
                     const float* __restrict__ x, float* __restrict__ out) {
  const int bid = blockIdx.x, tid = threadIdx.x;
  const int b = bid >> 6, oc = bid & 63;
  const int sub = tid / 288;
  const int r = tid - sub * 288;
  const int y = r / 12, x0 = (r % 12) * 2;
  __shared__ __align__(16) char smem[4096];

  h2* Wl = (h2*)smem;                 // [32 rows][16 h2] (9 used, 64B rows)
  for (int j = tid; j < 288; j += 576) {
    int icp = j / 9, rem = j - icp * 9;
    Wl[icp * 16 + rem] = woh[oc * 288 + j];
  }
  __syncthreads();

  float a0 = 0.f, a1 = 0.f;
  const int icp0 = sub * 16;
  const int yo = y * 28 + x0;
  const h2* dbase = outv + ((size_t)(b * 32 + icp0) * PPLANE + yo);
#pragma unroll
  for (int i = 0; i < 16; ++i) {
    const h2* dp = dbase + (size_t)i * PPLANE;
    h4 r0a = *(const h4*)(dp);      h4 r0b = *(const h4*)(dp + 2);
    h4 r1a = *(const h4*)(dp + 28); h4 r1b = *(const h4*)(dp + 30);
    h4 r2a = *(const h4*)(dp + 56); h4 r2b = *(const h4*)(dp + 58);
    const h2* wrow = Wl + (icp0 + i) * 16;
    // size-consistent union: v8[3] = 24 halves == v2[12] = 24 halves.
    union { h8 v8[3]; h2 v2[12]; } W;
    W.v8[0] = *(const h8*)(wrow);
    W.v8[1] = *(const h8*)(wrow + 4);
    W.v8[2] = *(const h8*)(wrow + 8);
    a0 = dot2(lo2(r0a), W.v2[0], a0);  a1 = dot2(hi2(r0a), W.v2[0], a1);
    a0 = dot2(hi2(r0a), W.v2[1], a0);  a1 = dot2(lo2(r0b), W.v2[1], a1);
    a0 = dot2(lo2(r0b), W.v2[2], a0);  a1 = dot2(hi2(r0b), W.v2[2], a1);
    a0 = dot2(lo2(r1a), W.v2[3], a0);  a1 = dot2(hi2(r1a), W.v2[3], a1);
    a0 = dot2(hi2(r1a), W.v2[4], a0);  a1 = dot2(lo2(r1b), W.v2[4], a1);
    a0 = dot2(lo2(r1b), W.v2[5], a0);  a1 = dot2(hi2(r1b), W.v2[5], a1);
    a0 = dot2(lo2(r2a), W.v2[6], a0);  a1 = dot2(hi2(r2a), W.v2[6], a1);
    a0 = dot2(hi2(r2a), W.v2[7], a0);  a1 = dot2(lo2(r2b), W.v2[7], a1);
    a0 = dot2(lo2(r2b), W.v2[8], a0);  a1 = dot2(hi2(r2b), W.v2[8], a1);
  }
  __syncthreads();
  float* cb = (float*)smem;           // [288][2]
  if (sub == 1) { cb[r * 2] = a0; cb[r * 2 + 1] = a1; }
  __syncthreads();
  if (sub == 0) {
    size_t idx = ((size_t)(b * C_IN + oc) * HW_) + y * 24 + x0;
    float2 xr = *reinterpret_cast<const float2*>(x + idx);
    const float inv = 1.f / 4096.f;
    float2 v;
    v.x = fmaf(a0 + cb[r * 2],     inv, xr.x);
    v.y = fmaf(a1 + cb[r * 2 + 1], inv, xr.y);
    *reinterpret_cast<float2*>(out + idx) = v;
  }
}

// ---------------- launch ---------------------------------------------------
extern "C" void kernel_launch(void* const* d_in, const int* in_sizes, int n_in,
                              void* d_out, int out_size, void* d_ws, size_t ws_size,
                              hipStream_t stream) {
  const float* x     = (const float*)d_in[0];
  const float* gamma = (const float*)d_in[1];
  const float* beta  = (const float*)d_in[2];
  const float* w_qkv = (const float*)d_in[3];
  const float* w_out = (const float*)d_in[4];
  float* out = (float*)d_out;

  h2* xh   = (h2*)d_ws;
  h2* wqh  = xh + XH_N;
  h2* woh  = wqh + WQH_N;
  h2* outv = woh + WOH_N;

  stats_pack_kernel<<<256, 256, 0, stream>>>(x, gamma, beta, w_qkv, w_out, xh, wqh, woh);
  qkv_attn_kernel<<<256, 576, 0, stream>>>(xh, wqh, outv);
  conv_out_kernel<<<256, 576, 0, stream>>>(outv, woh, x, out);
}